// Round 4
// baseline (123.560 us; speedup 1.0000x reference)
//
#include <hip/hip_runtime.h>
#include <math.h>

// TeacherMLP fused forward.
// R14 = R12's skeleton (512 x 1024, K/4, 4 rows/block, same LDS layout and
// barrier structure -- passed twice) with the hidden-layer math switched to
// FULLY SCALAR Pade(5,4) tanh: tanh z = z(945+105t+t^2)/(945+420t+15t^2),
// t=z^2, merged 8 terms per rcp via a num/den tree. ZERO inline asm in
// mlp_kernel. Rationale: R9/R11/R13 all failed with absmax ~50 and the one
// shared property is deep chains of hand-emitted v_pk_*_f32 inline asm under
// register pressure (R13's math re-verified correct; R12 passed identical
// dataflow). This removes the miscompile class AND removes 512 exp2/thread.
//   trans-bound theory -> mlp 52.6 -> 38-45us
//   VALU-issue theory  -> mlp ~38-45us too (scalar floor ~34us), VALUBusy 85%+
// Either way the VALUBusy/trans readout decides R15 (re-pack to VOP3P, float
// floor ~20-25us, now with proven-correct math).
// Accuracy: Pade err < 2e-5 for |z|<=2 (layer-0 max |z| ~2.3), +1.7e-2 at the
// unreachable corner z=6; better than the fast-exp2 path that passed at 0.03.

typedef float v2f __attribute__((ext_vector_type(2)));

#define HCLAMP 12.0f
#define INV2PI 0.15915494309189535f
#define SCW    2.885390081777927f    /* only weff's tanh-atom uses exp2 */

__device__ __forceinline__ float fast_rcp(float x)  { return __builtin_amdgcn_rcpf(x); }
__device__ __forceinline__ float fast_exp2(float x) { return __builtin_amdgcn_exp2f(x); }
__device__ __forceinline__ v2f pk2(float a, float b) { v2f r; r.x = a; r.y = b; return r; }

__global__ void weff_kernel(const float* __restrict__ W0, const int* __restrict__ I0,
                            const float* __restrict__ W1, const int* __restrict__ I1,
                            const float* __restrict__ W2, const int* __restrict__ I2,
                            float* __restrict__ ws) {
    int tid = blockIdx.x * blockDim.x + threadIdx.x;   // 0 .. 163839
    const float* W; const int* I; float* out; int outd; int e;
    if (tid < 65536)        { W = W0; I = I0; out = ws;          outd = 256; e = tid; }
    else if (tid < 131072)  { W = W1; I = I1; out = ws + 65536;  outd = 256; e = tid - 65536; }
    else if (tid < 163840)  { W = W2; I = I2; out = ws + 131072; outd = 128; e = tid - 131072; }
    else return;
    int o = e >> 8;       // out index (in-dim always 256)
    int i = e & 255;      // in index
    float w = W[e];       // coalesced (e = o*256 + i)
    int idx = I[e];
    // branchless atoms: [id, sin, tanh, square]
    float sn = __builtin_amdgcn_sinf(w * INV2PI);
    float th = 1.0f - 2.0f * fast_rcp(fast_exp2(w * SCW) + 1.0f);
    float sq = w * w;
    float v = (idx == 1) ? sn : (idx == 2) ? th : (idx == 3) ? sq : w;
    // packed store: [i/4][o][i%4] -> main loop reads float4 of 4 K-values
    out[(i >> 2) * (outd * 4) + o * 4 + (i & 3)] = v;
}

// ---- scalar Pade(5,4) tanh as (num, den) ----
__device__ __forceinline__ void pade_nd(float z, float& n, float& d) {
    float t = z * z;
    n = z * fmaf(t, t + 105.0f, 945.0f);          // z(t^2 + 105t + 945)
    d = fmaf(t, fmaf(t, 15.0f, 420.0f), 945.0f);  // 15t^2 + 420t + 945
}
__device__ __forceinline__ float nd2_n(float n0, float d0, float n1, float d1) {
    return fmaf(n0, d1, n1 * d0);
}

// 8 tanh terms for one row, merged with ONE rcp: acc += sum_k tanh(h_k*w_k).
__device__ __forceinline__ float row8_acc(
    float h0, float h1, float h2, float h3,
    float h4, float h5, float h6, float h7,
    float4 wA, float4 wB, float acc) {
    float n0, d0, n1, d1, n2, d2, n3, d3, n4, d4, n5, d5, n6, d6, n7, d7;
    pade_nd(h0 * wA.x, n0, d0);
    pade_nd(h1 * wA.y, n1, d1);
    pade_nd(h2 * wA.z, n2, d2);
    pade_nd(h3 * wA.w, n3, d3);
    pade_nd(h4 * wB.x, n4, d4);
    pade_nd(h5 * wB.y, n5, d5);
    pade_nd(h6 * wB.z, n6, d6);
    pade_nd(h7 * wB.w, n7, d7);
    float na = nd2_n(n0, d0, n1, d1), da = d0 * d1;
    float nb = nd2_n(n2, d2, n3, d3), db = d2 * d3;
    float nc = nd2_n(n4, d4, n5, d5), dc = d4 * d5;
    float ne_ = nd2_n(n6, d6, n7, d7), de_ = d6 * d7;
    float nf = nd2_n(na, da, nb, db), df = da * db;
    float ng = nd2_n(nc, dc, ne_, de_), dg = dc * de_;
    float nh = nd2_n(nf, df, ng, dg), dh = df * dg;
    return fmaf(nh, fast_rcp(dh), acc);
}

__global__ __launch_bounds__(1024, 4) void mlp_kernel(
    const float* __restrict__ x,  const float* __restrict__ b0,
    const float* __restrict__ b1, const float* __restrict__ b2,
    const float* __restrict__ ws, float* __restrict__ out) {
    const float4* We0 = (const float4*)ws;             // [64][256] packed [ic][o][4]
    const float4* We1 = (const float4*)(ws + 65536);   // [64][256]
    const float4* We2 = (const float4*)(ws + 131072);  // [64][128]

    __shared__ __align__(16) v2f hA0[256];      // pair0: rows (row0, row0+1)
    __shared__ __align__(16) v2f hA1[256];      // pair1: rows (row0+2, row0+3)
    __shared__ __align__(16) v2f hB0[256];
    __shared__ __align__(16) v2f hB1[256];
    __shared__ __align__(16) v2f partA[1024];   // split-K partials, pair 0
    __shared__ __align__(16) v2f partB[1024];   // pair 1

    const int t = threadIdx.x;     // 0..1023
    const int g = t >> 8;          // K-group 0..3 (wave-uniform)
    const int o = t & 255;         // neuron
    const int p = g >> 1;          // pair select (staging/epilogue role)
    const int l = g & 1;           // lane within pair
    const int row0 = blockIdx.x * 4;

    // stage 4 input rows: thread (g,o) stages row row0+2p+l, column o.
    {
        float xv = x[(row0 + 2 * p + l) * 256 + o];
        xv = fminf(fmaxf(xv, -HCLAMP), HCLAMP);
        ((float*)((p ? hA1 : hA0) + o))[l] = xv;
    }
    __syncthreads();

    // ---------------- layer 0: hA* -> hB* ----------------
    {
        const float bias = b0[o];
        float a0 = 0.f, a1 = 0.f, a2 = 0.f, a3 = 0.f;   // rows 0..3
#pragma unroll 1
        for (int icc = 0; icc < 16; icc += 2) {
            int ic = g * 16 + icc;
            float4 w0 = We0[ic * 256 + o];
            float4 w1 = We0[(ic + 1) * 256 + o];
            const float4* hp0 = (const float4*)(hA0 + ic * 4);
            const float4* hp1 = (const float4*)(hA1 + ic * 4);
            float4 pa = hp0[0], pb = hp0[1], pc = hp0[2], pd = hp0[3];
            float4 qa = hp1[0], qb = hp1[1], qc = hp1[2], qd = hp1[3];
            a0 = row8_acc(pa.x, pa.z, pb.x, pb.z, pc.x, pc.z, pd.x, pd.z, w0, w1, a0);
            a1 = row8_acc(pa.y, pa.w, pb.y, pb.w, pc.y, pc.w, pd.y, pd.w, w0, w1, a1);
            a2 = row8_acc(qa.x, qa.z, qb.x, qb.z, qc.x, qc.z, qd.x, qd.z, w0, w1, a2);
            a3 = row8_acc(qa.y, qa.w, qb.y, qb.w, qc.y, qc.w, qd.y, qd.w, w0, w1, a3);
        }
        partA[g * 256 + o] = pk2(a0, a1);
        partB[g * 256 + o] = pk2(a2, a3);
        __syncthreads();
        const v2f* prt = p ? partB : partA;
        float s = ((const float*)(prt + o))[l]
                + ((const float*)(prt + 256 + o))[l]
                + ((const float*)(prt + 512 + o))[l]
                + ((const float*)(prt + 768 + o))[l];
        float h = s + bias;                      // s = sum of 256 tanh terms
        h = fminf(fmaxf(h, -HCLAMP), HCLAMP);
        ((float*)((p ? hB1 : hB0) + o))[l] = h;
        __syncthreads();
    }

    // ---------------- layer 1: hB* -> (hA0, hB1) ----------------
    {
        const float bias = b1[o];
        float a0 = 0.f, a1 = 0.f, a2 = 0.f, a3 = 0.f;
#pragma unroll 1
        for (int icc = 0; icc < 16; icc += 2) {
            int ic = g * 16 + icc;
            float4 w0 = We1[ic * 256 + o];
            float4 w1 = We1[(ic + 1) * 256 + o];
            const float4* hp0 = (const float4*)(hB0 + ic * 4);
            const float4* hp1 = (const float4*)(hB1 + ic * 4);
            float4 pa = hp0[0], pb = hp0[1], pc = hp0[2], pd = hp0[3];
            float4 qa = hp1[0], qb = hp1[1], qc = hp1[2], qd = hp1[3];
            a0 = row8_acc(pa.x, pa.z, pb.x, pb.z, pc.x, pc.z, pd.x, pd.z, w0, w1, a0);
            a1 = row8_acc(pa.y, pa.w, pb.y, pb.w, pc.y, pc.w, pd.y, pd.w, w0, w1, a1);
            a2 = row8_acc(qa.x, qa.z, qb.x, qb.z, qc.x, qc.z, qd.x, qd.z, w0, w1, a2);
            a3 = row8_acc(qa.y, qa.w, qb.y, qb.w, qc.y, qc.w, qd.y, qd.w, w0, w1, a3);
        }
        partA[g * 256 + o] = pk2(a0, a1);
        partB[g * 256 + o] = pk2(a2, a3);
        __syncthreads();
        const v2f* prt = p ? partB : partA;
        float s = ((const float*)(prt + o))[l]
                + ((const float*)(prt + 256 + o))[l]
                + ((const float*)(prt + 512 + o))[l]
                + ((const float*)(prt + 768 + o))[l];
        float h = s + bias;
        h = fminf(fmaxf(h, -HCLAMP), HCLAMP);
        // pair0 -> hA0, pair1 -> hB1 (hB1's inner-loop reads completed before
        // the barrier above; hA1 stays untouched to avoid any WAR surprise).
        ((float*)((p ? hB1 : hA0) + o))[l] = h;
        __syncthreads();
    }

    // ---------------- layer 2: (hA0 pair0, hB1 pair1) -> out ----------------
    {
        const int o2 = t & 127;
        const int q  = t >> 7;     // K-eighth 0..7
        float c0 = 0.f, c1 = 0.f, c2 = 0.f, c3 = 0.f;
#pragma unroll 4
        for (int icc = 0; icc < 8; icc++) {
            int ic = q * 8 + icc;
            float4 w = We2[ic * 128 + o2];
            const float4* hp0 = (const float4*)(hA0 + ic * 4);
            const float4* hp1 = (const float4*)(hB1 + ic * 4);
            float4 pa = hp0[0], pb = hp0[1];
            float4 qa = hp1[0], qb = hp1[1];
            c0 = fmaf(pa.x, w.x, fmaf(pa.z, w.y, fmaf(pb.x, w.z, fmaf(pb.z, w.w, c0))));
            c1 = fmaf(pa.y, w.x, fmaf(pa.w, w.y, fmaf(pb.y, w.z, fmaf(pb.w, w.w, c1))));
            c2 = fmaf(qa.x, w.x, fmaf(qa.z, w.y, fmaf(qb.x, w.z, fmaf(qb.z, w.w, c2))));
            c3 = fmaf(qa.y, w.x, fmaf(qa.w, w.y, fmaf(qb.y, w.z, fmaf(qb.w, w.w, c3))));
        }
        partA[q * 128 + o2] = pk2(c0, c1);
        partB[q * 128 + o2] = pk2(c2, c3);
        __syncthreads();
        // 512 outputs (4 rows x 128), one per thread in the first half-block.
        if (t < 512) {
            const int r  = t >> 7;        // 0..3 -> row row0 + r
            const int oo = t & 127;
            const v2f* prt = (r & 2) ? partB : partA;
            const int  ln  = r & 1;
            float s = 0.0f;
#pragma unroll
            for (int q2 = 0; q2 < 8; q2++)
                s += ((const float*)(prt + q2 * 128 + oo))[ln];
            out[(row0 + r) * 128 + oo] = s + b2[oo];
        }
    }
}

extern "C" void kernel_launch(void* const* d_in, const int* in_sizes, int n_in,
                              void* d_out, int out_size, void* d_ws, size_t ws_size,
                              hipStream_t stream) {
    const float* x  = (const float*)d_in[0];
    const float* W0 = (const float*)d_in[1];
    const float* b0 = (const float*)d_in[2];
    const int*   I0 = (const int*)  d_in[3];
    const float* W1 = (const float*)d_in[4];
    const float* b1 = (const float*)d_in[5];
    const int*   I1 = (const int*)  d_in[6];
    const float* W2 = (const float*)d_in[7];
    const float* b2 = (const float*)d_in[8];
    const int*   I2 = (const int*)  d_in[9];
    float* ws  = (float*)d_ws;    // 163840 floats = 655360 B
    float* out = (float*)d_out;

    weff_kernel<<<640, 256, 0, stream>>>(W0, I0, W1, I1, W2, I2, ws);
    mlp_kernel<<<512, 1024, 0, stream>>>(x, b0, b1, b2, ws, out);
}